// Round 10
// baseline (224.897 us; speedup 1.0000x reference)
//
#include <hip/hip_runtime.h>

typedef unsigned int u32;
typedef _Float16 f16x8  __attribute__((ext_vector_type(8)));
typedef float    f32x16 __attribute__((ext_vector_type(16)));
typedef _Float16 v2h  __attribute__((ext_vector_type(2)));
typedef __fp16   v2fp __attribute__((ext_vector_type(2)));

#define E_TOT 160000
#define TPB   256
#define NBLK  625         // 256 edges per block: 4 waves x 2 tiles x 32 edges

// ================= ws layout (u32) =================
// pair bases: p00=0, p10=2048, p01=4096, p11=6144
//   per pair: W1A[32 rows][16u32]@+0 | W2A[32][16]@+512 | W3A[M'][16]@+1024
//   rows are OUTPUT dims; 16 u32 = 32 f16, k ascending in pairs (2s,2s+1).
//   W1A/W2A physical row p stores ORIGINAL row MU(p), where MU swaps row
//   blocks [4..7]<->[8..11] and [20..23]<->[24..27] (p^12 when bit2^bit3).
//   WHY: MFMA C-frag gives lane(hi) rows {8q+4hi+j}; next layer's B-frag
//   needs k-labels {16kk+8hi+j}. With MU, the C-frag in NATURAL register
//   order IS the next B-frag after relu+pack -- no cross-lane exchange, no
//   LDS, no permlane (R9's permlane direction bet failed correctness).
//   W1A row o: k<17 -> w1[k][o]; k==17 -> b1[o]; k>17 -> 0  (bias via x[17]=1)
//   W3A k-columns natural; rows PERMUTED: nf=1 pairs: row' = i*8+o (M'=64)
//                                        p11: row' = (i*3+f)*8+o (M'=192)
// bias region (f16 pairs): p00@10240(b2) 10256(b3) | p10@10288/10304 |
//   p01@10336/10352 | p11@10384(b2) 10400..10496(b3)
//   b2 pairs stored MU-permuted (match W2A physical rows); b3 natural-permuted
//   by the W3 row' scheme as before.
// MFMA orientation: D[out][edge]. Verified C/D map: col=lane&31,
// row=(reg&3)+8*(reg>>2)+4*(lane>>5).
// ILP-2: each wave runs TWO independent 32-edge tiles; weight fragments
// loaded once, fed to both (2 indep chains hide MFMA/L2 latency).

#define MFMA(a,b,c) __builtin_amdgcn_mfma_f32_32x32x16_f16((a),(b),(c),0,0,0)

__device__ __forceinline__ u32 pkh(float a, float b){
  union { v2fp h; u32 x; } u;
  u.h = __builtin_amdgcn_cvt_pkrtz(a, b);
  return u.x;
}
__device__ __forceinline__ v2h asvh(u32 x){
  union { u32 x; v2h h; } u; u.x = x; return u.h;
}
__device__ __forceinline__ int MU(int p){            // row block-swap involution
  return ((((p >> 2) ^ (p >> 3)) & 1) ? (p ^ 12) : p);
}

struct WPtrs { const float* p[24]; };  // (0,0),(1,0),(0,1),(1,1) x {w1,b1,w2,b2,w3,b3}

__global__ __launch_bounds__(256) void prep_kernel(WPtrs S, u32* __restrict__ ws)
{
  const int t = blockIdx.x*256 + threadIdx.x;
  if (t >= 10496) return;
  float a = 0.f, b = 0.f;
  if (t < 10240){
    const int pair = (t < 6144) ? (t >> 11) : 3;
    const int rel  = t - ((pair < 3) ? (pair << 11) : 6144);
    const float* __restrict__ w1 = S.p[pair*6+0];
    const float* __restrict__ b1 = S.p[pair*6+1];
    const float* __restrict__ w2 = S.p[pair*6+2];
    const float* __restrict__ w3 = S.p[pair*6+4];
    const int N3  = (pair < 3) ? 8  : 24;
    const int NC3 = (pair < 3) ? 64 : 192;
    if (rel < 512){                         // W1A (rows MU-permuted)
      int o = MU(rel >> 4), k0 = (rel & 15)*2;
      a = (k0   < 17) ? w1[k0*32 + o]     : ((k0   == 17) ? b1[o] : 0.f);
      b = (k0+1 < 17) ? w1[(k0+1)*32 + o] : ((k0+1 == 17) ? b1[o] : 0.f);
    } else if (rel < 1024){                 // W2A (rows MU-permuted, k natural)
      int j = rel - 512; int o = MU(j >> 4), k0 = (j & 15)*2;
      a = w2[k0*32 + o]; b = w2[(k0+1)*32 + o];
    } else {                                // W3A (k natural, rows i*8+o-permuted)
      int j = rel - 1024; int rp = j >> 4, k0 = (j & 15)*2;
      int col = (rp & 7)*N3 + (rp >> 3);
      a = w3[k0*NC3 + col]; b = w3[(k0+1)*NC3 + col];
    }
  } else {                                  // bias region
    const int rel  = t - 10240;
    const int pair = (rel < 144) ? (rel / 48) : 3;
    const int r2   = rel - ((pair < 3) ? pair*48 : 144);
    const float* __restrict__ b2 = S.p[pair*6+3];
    const float* __restrict__ b3 = S.p[pair*6+5];
    const int N3 = (pair < 3) ? 8 : 24;
    if (r2 < 16){                           // b2 pairs MU-permuted
      a = b2[MU(2*r2)]; b = b2[MU(2*r2+1)];
    } else {
      int r0 = (r2-16)*2, r1 = r0+1;        // b3: W3-row'-permuted
      a = b3[(r0 & 7)*N3 + (r0 >> 3)];
      b = b3[(r1 & 7)*N3 + (r1 >> 3)];
    }
  }
  ws[t] = pkh(a, b);
}

// ---- fragment helpers ----
__device__ __forceinline__ f16x8 ldfrag(const u32* __restrict__ p){   // global dwordx4
  union { uint4 u; f16x8 h; } c;
  c.u = *(const uint4*)p;
  return c.h;
}
// C-init from f16 bias row block m (physical rows m*32 + 8q+4hi+0..3)
__device__ __forceinline__ f32x16 ldbias(const u32* __restrict__ ws, int base, int m, int hi){
  f32x16 c;
  #pragma unroll
  for (int q = 0; q < 4; ++q){
    uint2 v = *(const uint2*)(ws + base + m*16 + 4*q + 2*hi);
    v2h lo = asvh(v.x), hh = asvh(v.y);
    c[4*q+0] = (float)lo[0]; c[4*q+1] = (float)lo[1];
    c[4*q+2] = (float)hh[0]; c[4*q+3] = (float)hh[1];
  }
  return c;
}
// relu + f16-pack C-frag -> next-layer B-frags IN NATURAL REG ORDER.
// Correct because W rows are MU-permuted at prep: lane(hi) reg r holds
// original feature 16kk+8hi+j exactly in ascending reg order (8-case table
// verified for both hi halves). No cross-lane ops needed.
__device__ __forceinline__ void packfrag(const f32x16& c, f16x8& k0, f16x8& k1){
  union { uint4 u; f16x8 h; } a, b;
  a.u = make_uint4(pkh(fmaxf(c[0], 0.f),  fmaxf(c[1], 0.f)),
                   pkh(fmaxf(c[2], 0.f),  fmaxf(c[3], 0.f)),
                   pkh(fmaxf(c[4], 0.f),  fmaxf(c[5], 0.f)),
                   pkh(fmaxf(c[6], 0.f),  fmaxf(c[7], 0.f)));
  b.u = make_uint4(pkh(fmaxf(c[8], 0.f),  fmaxf(c[9], 0.f)),
                   pkh(fmaxf(c[10],0.f),  fmaxf(c[11],0.f)),
                   pkh(fmaxf(c[12],0.f),  fmaxf(c[13],0.f)),
                   pkh(fmaxf(c[14],0.f),  fmaxf(c[15],0.f)));
  k0 = a.h; k1 = b.h;
}

// L1+L2 for one pair, TWO tiles sharing weight fragments -> H2 frags in regs
__device__ __forceinline__ void mlp12_2(const u32* __restrict__ ws, int pb, int b2base,
                                        int row, int hi,
                                        const f16x8 (&bx0)[2], const f16x8 (&bx1)[2],
                                        f16x8 (&h0)[2], f16x8 (&h1)[2])
{
  const u32* W = ws + pb + row*16 + hi*4;
  f16x8 wa = ldfrag(W), wb = ldfrag(W + 8);
  f16x8 g0[2], g1[2];
  #pragma unroll
  for (int t = 0; t < 2; ++t){
    f32x16 z;
    #pragma unroll
    for (int i = 0; i < 16; ++i) z[i] = 0.f;
    z = MFMA(wa, bx0[t], z);
    z = MFMA(wb, bx1[t], z);
    packfrag(z, g0[t], g1[t]);
  }
  f16x8 w2a = ldfrag(W + 512), w2b = ldfrag(W + 520);
  f32x16 bias = ldbias(ws, b2base, 0, hi);
  #pragma unroll
  for (int t = 0; t < 2; ++t){
    f32x16 z = bias;
    z = MFMA(w2a, g0[t], z);
    z = MFMA(w2b, g1[t], z);
    packfrag(z, h0[t], h1[t]);
  }
}

// L3 (M'=64, row'=i*8+o), TWO tiles sharing weights: acc[t][o'] += R[o][i]*v[t][i]
__device__ __forceinline__ void l3acc_2(const u32* __restrict__ ws, int w3base, int b3base,
                                        int row, int hi,
                                        const f16x8 (&h0)[2], const f16x8 (&h1)[2],
                                        const float (&v)[2][8], float (&acc)[2][4])
{
  #pragma unroll
  for (int m = 0; m < 2; ++m){
    f32x16 bias = ldbias(ws, b3base, m, hi);
    const u32* W = ws + w3base + (m*32 + row)*16 + hi*4;
    f16x8 wa = ldfrag(W), wb = ldfrag(W + 8);
    #pragma unroll
    for (int t = 0; t < 2; ++t){
      f32x16 c3 = bias;
      c3 = MFMA(wa, h0[t], c3);
      c3 = MFMA(wb, h1[t], c3);
      #pragma unroll
      for (int r = 0; r < 16; ++r)
        acc[t][r & 3] = fmaf(c3[r], v[t][4*m + (r >> 2)], acc[t][r & 3]);
    }
  }
}

// class-B (1,1) epilogue for ONE tile (sequential per tile to cap VGPR)
__device__ __forceinline__ void epiB(const u32* __restrict__ ws,
                                     const float* __restrict__ feat1,
                                     const float* __restrict__ b01,
                                     const float* __restrict__ b11,
                                     float* __restrict__ out,
                                     int e, int idx, int row, int hi,
                                     const float (&t01m)[4],
                                     f16x8 h0, f16x8 h1)
{
  float f1v[24];
  {
    const float4* f = (const float4*)(feat1 + (size_t)idx*24);
    #pragma unroll
    for (int j = 0; j < 6; ++j){
      float4 v = f[j];
      f1v[4*j+0]=v.x; f1v[4*j+1]=v.y; f1v[4*j+2]=v.z; f1v[4*j+3]=v.w;
    }
  }
  float Bv[27];
  {
    const float* __restrict__ bp = b11 + (size_t)e*27;
    #pragma unroll
    for (int j = 0; j < 27; ++j) Bv[j] = bp[j];
  }
  float B01q[3];
  #pragma unroll
  for (int q = 0; q < 3; ++q) B01q[q] = b01[(size_t)e*3 + q];
  float m1[12];
  #pragma unroll
  for (int o2 = 0; o2 < 4; ++o2)
    #pragma unroll
    for (int p = 0; p < 3; ++p)
      m1[o2*3+p] = t01m[o2] * B01q[p];
  #pragma unroll
  for (int m = 0; m < 6; ++m){            // 6 M-tiles of W3(1,1), row'=(i*3+f)*8+o
    f32x16 c3 = ldbias(ws, 10400, m, hi);
    const u32* W = ws + 7168 + (m*32 + row)*16 + hi*4;
    c3 = MFMA(ldfrag(W),     h0, c3);
    c3 = MFMA(ldfrag(W + 8), h1, c3);
    float C1[4][3];
    #pragma unroll
    for (int t2 = 0; t2 < 4; ++t2){
      const int ifp = 4*m + t2;
      const int ii = ifp / 3, ff = ifp - 3*ii;
      #pragma unroll
      for (int p = 0; p < 3; ++p)
        C1[t2][p] = fmaf(Bv[p*9 + 0 + ff], f1v[ii*3 + 0],
                    fmaf(Bv[p*9 + 3 + ff], f1v[ii*3 + 1],
                         Bv[p*9 + 6 + ff] * f1v[ii*3 + 2]));
    }
    #pragma unroll
    for (int r = 0; r < 16; ++r)
      #pragma unroll
      for (int p = 0; p < 3; ++p)
        m1[(r & 3)*3 + p] = fmaf(c3[r], C1[r >> 2][p], m1[(r & 3)*3 + p]);
  }
  float* o1 = out + (size_t)E_TOT*8 + (size_t)e*24 + 12*hi;
  ((float4*)o1)[0] = make_float4(m1[0], m1[1], m1[2],  m1[3]);
  ((float4*)o1)[1] = make_float4(m1[4], m1[5], m1[6],  m1[7]);
  ((float4*)o1)[2] = make_float4(m1[8], m1[9], m1[10], m1[11]);
}

__global__ __launch_bounds__(TPB, 2) void edge_kernel(
    const float* __restrict__ feat0, const float* __restrict__ feat1,
    const float* __restrict__ wE,    const float* __restrict__ radial,
    const float* __restrict__ b00,   const float* __restrict__ b01,
    const float* __restrict__ b10,   const float* __restrict__ b11,
    const int* __restrict__ src_idx, const u32* __restrict__ ws,
    float* __restrict__ out)
{
  const int tid = threadIdx.x;
  const int w   = tid >> 6;
  const int hi  = (tid >> 5) & 1;
  const int row = tid & 31;               // = lane&31 = edge col / A-row
  const int e0  = blockIdx.x*256 + w*64 + row;   // tile t: e0 + 32t

  int idx[2];
  f16x8 bx0[2], bx1[2];
  #pragma unroll
  for (int t = 0; t < 2; ++t){
    const int e = e0 + 32*t;
    idx[t] = src_idx[e];
    const float4* wp = (const float4*)(wE + (size_t)e*16 + 8*hi);
    float4 x0 = wp[0], x1 = wp[1];
    union { uint4 u; f16x8 h; } cc;
    cc.u = make_uint4(pkh(x0.x,x0.y), pkh(x0.z,x0.w), pkh(x1.x,x1.y), pkh(x1.z,x1.w));
    bx0[t] = cc.h;                        // k = 8hi..8hi+7
    cc.u = make_uint4(hi ? 0u : pkh(radial[e], 1.0f), 0u, 0u, 0u);
    bx1[t] = cc.h;                        // k16=radial, k17=1 (bias), rest 0
  }
  float f0v[2][8];
  #pragma unroll
  for (int t = 0; t < 2; ++t){
    const float4* f = (const float4*)(feat0 + (size_t)idx[t]*8);
    float4 u0 = f[0], u1 = f[1];
    f0v[t][0]=u0.x; f0v[t][1]=u0.y; f0v[t][2]=u0.z; f0v[t][3]=u0.w;
    f0v[t][4]=u1.x; f0v[t][5]=u1.y; f0v[t][6]=u1.z; f0v[t][7]=u1.w;
  }
  float Uv[2][8], bB[2];
  #pragma unroll
  for (int t = 0; t < 2; ++t){            // f1v scoped: not live past Uv
    const int e = e0 + 32*t;
    bB[t] = b00[e];
    float B10q[3];
    #pragma unroll
    for (int q = 0; q < 3; ++q) B10q[q] = b10[(size_t)e*3 + q];
    float f1t[24];
    const float4* f = (const float4*)(feat1 + (size_t)idx[t]*24);
    #pragma unroll
    for (int j = 0; j < 6; ++j){
      float4 v = f[j];
      f1t[4*j+0]=v.x; f1t[4*j+1]=v.y; f1t[4*j+2]=v.z; f1t[4*j+3]=v.w;
    }
    #pragma unroll
    for (int i = 0; i < 8; ++i)
      Uv[t][i] = fmaf(B10q[0], f1t[3*i], fmaf(B10q[1], f1t[3*i+1], B10q[2]*f1t[3*i+2]));
  }

  f16x8 h0[2], h1[2];
  // ================= class A: (0,0) + (1,0) -> out0 =================
  float mA[2][4];
  #pragma unroll
  for (int t = 0; t < 2; ++t)
    #pragma unroll
    for (int j = 0; j < 4; ++j) mA[t][j] = 0.f;
  mlp12_2(ws,    0, 10240, row, hi, bx0, bx1, h0, h1);
  l3acc_2(ws, 1024, 10256, row, hi, h0, h1, f0v, mA);
  #pragma unroll
  for (int t = 0; t < 2; ++t)
    #pragma unroll
    for (int j = 0; j < 4; ++j) mA[t][j] *= bB[t];   // basis_0_0 scalar
  mlp12_2(ws, 2048, 10288, row, hi, bx0, bx1, h0, h1);
  l3acc_2(ws, 3072, 10304, row, hi, h0, h1, Uv, mA);
  #pragma unroll
  for (int t = 0; t < 2; ++t){
    const int e = e0 + 32*t;
    *(float4*)(out + (size_t)e*8 + 4*hi) = make_float4(mA[t][0], mA[t][1], mA[t][2], mA[t][3]);
  }

  // ================= class B: (0,1) + (1,1) -> out1 =================
  float t01m[2][4];
  #pragma unroll
  for (int t = 0; t < 2; ++t)
    #pragma unroll
    for (int j = 0; j < 4; ++j) t01m[t][j] = 0.f;
  mlp12_2(ws, 4096, 10336, row, hi, bx0, bx1, h0, h1);
  l3acc_2(ws, 5120, 10352, row, hi, h0, h1, f0v, t01m);
  mlp12_2(ws, 6144, 10384, row, hi, bx0, bx1, h0, h1);   // (1,1) H2 in h0/h1
  {
    float t0[4] = {t01m[0][0], t01m[0][1], t01m[0][2], t01m[0][3]};
    epiB(ws, feat1, b01, b11, out, e0,      idx[0], row, hi, t0, h0[0], h1[0]);
    float t1[4] = {t01m[1][0], t01m[1][1], t01m[1][2], t01m[1][3]};
    epiB(ws, feat1, b01, b11, out, e0 + 32, idx[1], row, hi, t1, h0[1], h1[1]);
  }
}

extern "C" void kernel_launch(void* const* d_in, const int* in_sizes, int n_in,
                              void* d_out, int out_size, void* d_ws, size_t ws_size,
                              hipStream_t stream)
{
  const float* feat0 = (const float*)d_in[0];
  const float* feat1 = (const float*)d_in[1];
  const float* wE    = (const float*)d_in[2];
  const float* rad   = (const float*)d_in[3];
  const float* b00   = (const float*)d_in[4];
  const float* b01   = (const float*)d_in[11];
  const float* b10   = (const float*)d_in[18];
  const float* b11   = (const float*)d_in[25];
  const int* sidx    = (const int*)d_in[32];
  u32* ws            = (u32*)d_ws;

  // ws pair order: (0,0), (1,0), (0,1), (1,1) -> d_in weight bases 5, 19, 12, 26
  const int base[4] = {5, 19, 12, 26};
  WPtrs S;
  for (int p = 0; p < 4; ++p)
    for (int k = 0; k < 6; ++k)
      S.p[p*6 + k] = (const float*)d_in[base[p] + k];

  prep_kernel<<<41, 256, 0, stream>>>(S, ws);
  edge_kernel<<<NBLK, TPB, 0, stream>>>(feat0, feat1, wE, rad, b00, b01, b10, b11,
                                        sidx, ws, (float*)d_out);
}